// Round 7
// baseline (147.638 us; speedup 1.0000x reference)
//
#include <hip/hip_runtime.h>
#include <hip/hip_bf16.h>

// Problem constants
#define B_   4
#define N_   160
#define D_   64
#define ZI_  64
#define H1_  128
#define H2_  64
#define L_   4
#define LE_  8

typedef __bf16 bf16x8 __attribute__((ext_vector_type(8)));
typedef float  f32x4  __attribute__((ext_vector_type(4)));
typedef unsigned int u32x4 __attribute__((ext_vector_type(4)));

static __device__ __forceinline__ unsigned pk_bf16(float a, float b) {
    __hip_bfloat162 h = __float22bfloat162_rn(float2{a, b});
    union { __hip_bfloat162 h; unsigned u; } c;
    c.h = h;
    return c.u;
}

// ---------------------------------------------------------------------------
// Stage A: per-(b,i) precompute (scalar; ~3 µs).
//   ui[b,i,h]   = ne[b,i]@Wi1[:64] + z_intra[b]@Wi1[128:192] + bi1      (fp32)
//   uq[b,l,i,h] = ne[b,i]@Wl1[:64] + z_inter[b]@Wl1[128:192] + lag[l]@Wl1_l + bl1
//   vpi/vpl     = bf16 j-panels, stored PRE-SWIZZLED: logical element h of
//                 row bi lands at granule (h>>3)^(bi&7), elem h&7. Stage_b
//                 then stages panels with a straight global_load_lds copy and
//                 reads with the same XOR formula (conflict-free, no ds_write).
// Blocks 0/1 also emit Wi2/Wl2 as bf16 MFMA-B-fragment-ordered arrays.
// ---------------------------------------------------------------------------
__global__ __launch_bounds__(128) void stage_a(
    const float* __restrict__ ne,
    const float* __restrict__ zi,
    const float* __restrict__ ze,
    const float* __restrict__ lag,
    const float* __restrict__ Wi1,
    const float* __restrict__ bi1,
    const float* __restrict__ Wl1,
    const float* __restrict__ bl1,
    const float* __restrict__ Wi2,
    const float* __restrict__ Wl2,
    float* __restrict__ ui, float* __restrict__ uq,
    __bf16* __restrict__ vpi, __bf16* __restrict__ vpl,
    __bf16* __restrict__ W2fi, __bf16* __restrict__ W2fl)
{
    const int bi = blockIdx.x;       // b*N + i
    const int b  = bi / N_;
    const int h  = threadIdx.x;      // 0..127

    const float* nerow = ne + bi * D_;

    float pi_ = 0.f, pj_ = 0.f, qi_ = 0.f, qj_ = 0.f;
#pragma unroll 16
    for (int d = 0; d < D_; ++d) {
        const float a = nerow[d];
        pi_ += a * Wi1[d * H1_ + h];
        pj_ += a * Wi1[(D_ + d) * H1_ + h];
        qi_ += a * Wl1[d * H1_ + h];
        qj_ += a * Wl1[(D_ + d) * H1_ + h];
    }
    float pz = 0.f, qz = 0.f;
#pragma unroll 16
    for (int z = 0; z < ZI_; ++z) {
        pz += zi[b * ZI_ + z] * Wi1[(2 * D_ + z) * H1_ + h];
        qz += ze[b * ZI_ + z] * Wl1[(2 * D_ + z) * H1_ + h];
    }

    ui[bi * H1_ + h] = pi_ + pz + bi1[h];

    // Pre-swizzled panel store (row&7 == bi&7 since N and B*N are mult of 8).
    const int hsw = (((h >> 3) ^ (bi & 7)) << 3) | (h & 7);
    vpi[bi * H1_ + hsw] = (__bf16)pj_;
    vpl[bi * H1_ + hsw] = (__bf16)qj_;

    const float qbase = qi_ + qz + bl1[h];
#pragma unroll
    for (int l = 0; l < L_; ++l) {
        float ql = 0.f;
#pragma unroll
        for (int e = 0; e < LE_; ++e)
            ql += lag[l * LE_ + e] * Wl1[(2 * D_ + ZI_ + e) * H1_ + h];
        uq[((b * L_ + l) * N_ + (bi % N_)) * H1_ + h] = qbase + ql;
    }

    // W2 -> bf16 fragment layout: chunk fc = (kt*4+ct)*64 + lane holds the 8
    // values lane needs for fragment (kt,ct).
    if (bi < 2) {
        const float* Wsrc = (bi == 0) ? Wi2 : Wl2;
        __bf16* Wdst = (bi == 0) ? W2fi : W2fl;
#pragma unroll
        for (int r = 0; r < 8; ++r) {
            const int fc = h + 128 * r;
            const int kt = fc >> 8, ct = (fc >> 6) & 3;
            const int q = (fc >> 4) & 3, c = fc & 15;
            bf16x8 t;
#pragma unroll
            for (int j = 0; j < 8; ++j)
                t[j] = (__bf16)Wsrc[(32 * kt + 8 * q + j) * H2_ + 16 * ct + c];
            *(bf16x8*)(Wdst + fc * 8) = t;
        }
    }
}

// ---------------------------------------------------------------------------
// Stage B (R7): R5 structure (800 blocks, 10 j-tiles) with
//  (1) panel staged via global_load_lds 16B DMA (no staging VGPRs/ds_write;
//      swizzle pre-baked in workspace by stage_a),
//  (2) packed a-build: dword unpack (<<16 / &0xffff0000), f32x4 pk adds/max,
//      v_cvt_pk_bf16_f32 pack,
//  (3) __launch_bounds__(256,4): <=128 VGPR -> 4 waves/SIMD, 4 blocks/CU
//      (4 x 40KB = 160KB LDS exactly). R2-R6 evidence: ~150 VGPR capped us
//      at 3 waves/SIMD and stage_b sat at ~26us of unhidden latency.
// MFMA 16x16x32 layouts (HW-verified):
//   A: lane holds A[m=lane&15][k=8*(lane>>4)+j]
//   B: lane holds B[k=8*(lane>>4)+j][n=lane&15]
//   C/D: lane holds D[row=4*(lane>>4)+reg][col=lane&15]
// ---------------------------------------------------------------------------
__global__ __launch_bounds__(256, 4) void stage_b(
    const float* __restrict__ ui, const float* __restrict__ uq,
    const __bf16* __restrict__ vpi, const __bf16* __restrict__ vpl,
    const __bf16* __restrict__ W2fi, const __bf16* __restrict__ W2fl,
    const float* __restrict__ bi2, const float* __restrict__ bi3,
    const float* __restrict__ bl2, const float* __restrict__ bl3,
    const float* __restrict__ Wi3, const float* __restrict__ Wl3,
    float* __restrict__ out)
{
    __shared__ __align__(16) __bf16 panel[N_ * H1_];   // 40960 B, swizzled

    const int t    = threadIdx.x;
    const int wid  = t >> 6;
    const int lane = t & 63;
    const int q = lane >> 4;
    const int c = lane & 15;

    const int blk  = blockIdx.x;         // 0..799
    const int wave = blk * 4 + wid;

    // Block-uniform panel + W2-fragment source.
    const __bf16 *psrc, *Wf;
    if (blk < 160) { psrc = vpi + (blk / 40) * (N_ * H1_);          Wf = W2fi; }
    else           { psrc = vpl + ((blk - 160) / 160) * (N_ * H1_); Wf = W2fl; }

    // 1) Panel -> LDS via async DMA, 16B/lane, straight copy (swizzle is
    //    pre-baked). Wave wid copies bytes [it*4096 + wid*1024, +1024).
    {
        const char* gp = (const char*)psrc;
        char* lp = (char*)panel;
#pragma unroll
        for (int it = 0; it < 10; ++it) {
            __builtin_amdgcn_global_load_lds(
                (const __attribute__((address_space(1))) void*)(gp + it * 4096 + t * 16),
                (__attribute__((address_space(3))) void*)(lp + it * 4096 + wid * 1024),
                16, 0, 0);
        }
    }

    // Wave-specific row params.
    const float* ubase;
    const float *b2, *w3;
    const float* b3p;
    long  obase;
    int   i;
    if (wave < B_ * N_) {                      // intra: W_t
        i = wave % N_;
        ubase = ui + wave * H1_;
        b2 = bi2; w3 = Wi3; b3p = bi3;
        obase = (long)wave * N_;
    } else {                                   // inter: A_lags_t
        const int w2i = wave - B_ * N_;
        i = w2i % N_;
        ubase = uq + w2i * H1_;
        b2 = bl2; w3 = Wl3; b3p = bl3;
        obase = (long)B_ * N_ * N_ + (long)w2i * N_;
    }
    const float b3f = b3p[0];

    // 2) W2 fragments: 16 coalesced 16B loads, register-resident.
    bf16x8 bfr[4][4];
#pragma unroll
    for (int kt = 0; kt < 4; ++kt)
#pragma unroll
        for (int ct = 0; ct < 4; ++ct)
            bfr[kt][ct] = *(const bf16x8*)(Wf + ((kt * 4 + ct) * 64 + lane) * 8);

    // u slices, split into even/odd k so they pair with dword-unpacked v.
    f32x4 ue[4], uo[4];
#pragma unroll
    for (int kt = 0; kt < 4; ++kt) {
        const f32x4 a0 = *(const f32x4*)(ubase + 32 * kt + 8 * q);
        const f32x4 a1 = *(const f32x4*)(ubase + 32 * kt + 8 * q + 4);
        ue[kt] = (f32x4){a0[0], a0[2], a1[0], a1[2]};
        uo[kt] = (f32x4){a0[1], a0[3], a1[1], a1[3]};
    }

    float b2c[4], w3c[4];
#pragma unroll
    for (int ct = 0; ct < 4; ++ct) {
        b2c[ct] = b2[16 * ct + c];
        w3c[ct] = w3[16 * ct + c];
    }

    __syncthreads();   // drains the global_load_lds DMA (vmcnt) + all waves

    // 3) Tile loop: LDS + registers only.
    for (int jt = 0; jt < 10; ++jt) {
        const __bf16* prow = panel + (16 * jt + c) * H1_;
        f32x4 acc[4];
#pragma unroll
        for (int ct = 0; ct < 4; ++ct)
            acc[ct] = (f32x4){b2c[ct], b2c[ct], b2c[ct], b2c[ct]};

#pragma unroll
        for (int kt = 0; kt < 4; ++kt) {
            const u32x4 vw = *(const u32x4*)(prow + (((4 * kt + q) ^ (c & 7)) << 3));
            // Unpack: dword d = [k=2d (lo16) | k=2d+1 (hi16)].
            f32x4 vlo, vhi;
#pragma unroll
            for (int d = 0; d < 4; ++d) {
                const unsigned lo = vw[d] << 16;
                const unsigned hi = vw[d] & 0xffff0000u;
                vlo[d] = __uint_as_float(lo);
                vhi[d] = __uint_as_float(hi);
            }
            f32x4 xe = ue[kt] + vlo;
            f32x4 xo = uo[kt] + vhi;
            xe = __builtin_elementwise_max(xe, (f32x4)0.f);
            xo = __builtin_elementwise_max(xo, (f32x4)0.f);
            union { bf16x8 v; unsigned d[4]; } a;
#pragma unroll
            for (int d = 0; d < 4; ++d)
                a.d[d] = pk_bf16(xe[d], xo[d]);
#pragma unroll
            for (int ct = 0; ct < 4; ++ct)
                acc[ct] = __builtin_amdgcn_mfma_f32_16x16x32_bf16(
                    a.v, bfr[kt][ct], acc[ct], 0, 0, 0);
        }

        // Epilogue: logit[r] = b3 + sum_col relu(H2pre) * w3 (b2 in acc).
        float logit[4];
#pragma unroll
        for (int r = 0; r < 4; ++r) {
            float p = 0.f;
#pragma unroll
            for (int ct = 0; ct < 4; ++ct)
                p += fmaxf(acc[ct][r], 0.f) * w3c[ct];
            p += __shfl_xor(p, 1);
            p += __shfl_xor(p, 2);
            p += __shfl_xor(p, 4);
            p += __shfl_xor(p, 8);
            logit[r] = p;
        }

        if (c < 4) {
            const int j = 16 * jt + 4 * q + c;
            const float lg = logit[c] + b3f;
            const float s = (j == i) ? 0.f : 1.f / (1.f + __expf(-lg));
            out[obase + j] = s;
        }
    }
}

// ---------------------------------------------------------------------------
extern "C" void kernel_launch(void* const* d_in, const int* in_sizes, int n_in,
                              void* d_out, int out_size, void* d_ws, size_t ws_size,
                              hipStream_t stream) {
    const float* ne  = (const float*)d_in[0];
    const float* zi  = (const float*)d_in[1];
    const float* ze  = (const float*)d_in[2];
    const float* lag = (const float*)d_in[3];
    const float* Wi1 = (const float*)d_in[4];
    const float* bi1 = (const float*)d_in[5];
    const float* Wi2 = (const float*)d_in[6];
    const float* bi2 = (const float*)d_in[7];
    const float* Wi3 = (const float*)d_in[8];
    const float* bi3 = (const float*)d_in[9];
    const float* Wl1 = (const float*)d_in[10];
    const float* bl1 = (const float*)d_in[11];
    const float* Wl2 = (const float*)d_in[12];
    const float* bl2 = (const float*)d_in[13];
    const float* Wl3 = (const float*)d_in[14];
    const float* bl3 = (const float*)d_in[15];

    float*  ws   = (float*)d_ws;
    float*  ui   = ws;                         // 640*128 fp32
    float*  uqw  = ws + 81920;                 // 2560*128 fp32
    __bf16* vpi  = (__bf16*)(ws + 409600);     // 640*128 bf16 (pre-swizzled)
    __bf16* vpl  = vpi + 81920;                // 640*128 bf16 (pre-swizzled)
    __bf16* W2fi = (__bf16*)(ws + 491520);     // 8192 bf16 (fragment order)
    __bf16* W2fl = W2fi + 8192;                // 8192 bf16

    stage_a<<<B_ * N_, 128, 0, stream>>>(ne, zi, ze, lag, Wi1, bi1, Wl1, bl1,
                                         Wi2, Wl2, ui, uqw, vpi, vpl, W2fi, W2fl);

    stage_b<<<(B_ * N_ + B_ * L_ * N_) / 4, 256, 0, stream>>>(
        ui, uqw, vpi, vpl, W2fi, W2fl,
        bi2, bi3, bl2, bl3, Wi3, Wl3,
        (float*)d_out);
}

// Round 8
// 115.260 us; speedup vs baseline: 1.2809x; 1.2809x over previous
//
#include <hip/hip_runtime.h>
#include <hip/hip_bf16.h>

// Problem constants
#define B_   4
#define N_   160
#define D_   64
#define ZI_  64
#define H1_  128
#define H2_  64
#define L_   4
#define LE_  8

typedef __bf16 bf16x8 __attribute__((ext_vector_type(8)));
typedef float  f32x4  __attribute__((ext_vector_type(4)));
typedef unsigned int u32x4 __attribute__((ext_vector_type(4)));

static __device__ __forceinline__ unsigned pk_bf16(float a, float b) {
    __hip_bfloat162 h = __float22bfloat162_rn(float2{a, b});
    union { __hip_bfloat162 h; unsigned u; } c;
    c.h = h;
    return c.u;
}

// ---------------------------------------------------------------------------
// Stage A: per-(b,i) precompute (scalar; ~3 µs).
//   ui[b,i,h]   = ne[b,i]@Wi1[:64] + z_intra[b]@Wi1[128:192] + bi1      (fp32)
//   uq[b,l,i,h] = ne[b,i]@Wl1[:64] + z_inter[b]@Wl1[128:192] + lag[l]@Wl1_l + bl1
//   vpi/vpl     = bf16 j-panels, stored PRE-SWIZZLED: logical element h of
//                 row bi lands at granule (h>>3)^(bi&7), elem h&7. Stage_b
//                 stages panels with a straight global_load_lds copy and
//                 reads with the same XOR formula (conflict-free, no ds_write).
// Blocks 0/1 also emit Wi2/Wl2 as bf16 MFMA-B-fragment-ordered arrays.
// ---------------------------------------------------------------------------
__global__ __launch_bounds__(128) void stage_a(
    const float* __restrict__ ne,
    const float* __restrict__ zi,
    const float* __restrict__ ze,
    const float* __restrict__ lag,
    const float* __restrict__ Wi1,
    const float* __restrict__ bi1,
    const float* __restrict__ Wl1,
    const float* __restrict__ bl1,
    const float* __restrict__ Wi2,
    const float* __restrict__ Wl2,
    float* __restrict__ ui, float* __restrict__ uq,
    __bf16* __restrict__ vpi, __bf16* __restrict__ vpl,
    __bf16* __restrict__ W2fi, __bf16* __restrict__ W2fl)
{
    const int bi = blockIdx.x;       // b*N + i
    const int b  = bi / N_;
    const int h  = threadIdx.x;      // 0..127

    const float* nerow = ne + bi * D_;

    float pi_ = 0.f, pj_ = 0.f, qi_ = 0.f, qj_ = 0.f;
#pragma unroll 16
    for (int d = 0; d < D_; ++d) {
        const float a = nerow[d];
        pi_ += a * Wi1[d * H1_ + h];
        pj_ += a * Wi1[(D_ + d) * H1_ + h];
        qi_ += a * Wl1[d * H1_ + h];
        qj_ += a * Wl1[(D_ + d) * H1_ + h];
    }
    float pz = 0.f, qz = 0.f;
#pragma unroll 16
    for (int z = 0; z < ZI_; ++z) {
        pz += zi[b * ZI_ + z] * Wi1[(2 * D_ + z) * H1_ + h];
        qz += ze[b * ZI_ + z] * Wl1[(2 * D_ + z) * H1_ + h];
    }

    ui[bi * H1_ + h] = pi_ + pz + bi1[h];

    // Pre-swizzled panel store (row&7 == bi&7 since N is a multiple of 8).
    const int hsw = (((h >> 3) ^ (bi & 7)) << 3) | (h & 7);
    vpi[bi * H1_ + hsw] = (__bf16)pj_;
    vpl[bi * H1_ + hsw] = (__bf16)qj_;

    const float qbase = qi_ + qz + bl1[h];
#pragma unroll
    for (int l = 0; l < L_; ++l) {
        float ql = 0.f;
#pragma unroll
        for (int e = 0; e < LE_; ++e)
            ql += lag[l * LE_ + e] * Wl1[(2 * D_ + ZI_ + e) * H1_ + h];
        uq[((b * L_ + l) * N_ + (bi % N_)) * H1_ + h] = qbase + ql;
    }

    // W2 -> bf16 fragment layout: chunk fc = (kt*4+ct)*64 + lane holds the 8
    // values lane needs for fragment (kt,ct).
    if (bi < 2) {
        const float* Wsrc = (bi == 0) ? Wi2 : Wl2;
        __bf16* Wdst = (bi == 0) ? W2fi : W2fl;
#pragma unroll
        for (int r = 0; r < 8; ++r) {
            const int fc = h + 128 * r;
            const int kt = fc >> 8, ct = (fc >> 6) & 3;
            const int q = (fc >> 4) & 3, c = fc & 15;
            bf16x8 t;
#pragma unroll
            for (int j = 0; j < 8; ++j)
                t[j] = (__bf16)Wsrc[(32 * kt + 8 * q + j) * H2_ + 16 * ct + c];
            *(bf16x8*)(Wdst + fc * 8) = t;
        }
    }
}

// ---------------------------------------------------------------------------
// Stage B (R8 = R7 minus the spill): 800 blocks, 10 j-tiles.
//  (1) panel staged via global_load_lds 16B DMA (swizzle pre-baked),
//  (2) packed a-build: dword unpack (<<16 / &0xffff0000), f32x4 adds/max,
//      v_cvt_pk_bf16_f32 pack — halves the ~3900 VALU instrs/wave the
//      scalar build generated (back-solved from VALUBusy=19% @ R2),
//  (3) __launch_bounds__(256,3): VGPR cap ~170. R7's (256,4) forced 64 arch
//      VGPRs -> ~10KB/wave scratch spills (WRITE_SIZE 33MB, dur 62us).
// MFMA 16x16x32 layouts (HW-verified):
//   A: lane holds A[m=lane&15][k=8*(lane>>4)+j]
//   B: lane holds B[k=8*(lane>>4)+j][n=lane&15]
//   C/D: lane holds D[row=4*(lane>>4)+reg][col=lane&15]
// ---------------------------------------------------------------------------
__global__ __launch_bounds__(256, 3) void stage_b(
    const float* __restrict__ ui, const float* __restrict__ uq,
    const __bf16* __restrict__ vpi, const __bf16* __restrict__ vpl,
    const __bf16* __restrict__ W2fi, const __bf16* __restrict__ W2fl,
    const float* __restrict__ bi2, const float* __restrict__ bi3,
    const float* __restrict__ bl2, const float* __restrict__ bl3,
    const float* __restrict__ Wi3, const float* __restrict__ Wl3,
    float* __restrict__ out)
{
    __shared__ __align__(16) __bf16 panel[N_ * H1_];   // 40960 B, swizzled

    const int t    = threadIdx.x;
    const int wid  = t >> 6;
    const int lane = t & 63;
    const int q = lane >> 4;
    const int c = lane & 15;

    const int blk  = blockIdx.x;         // 0..799
    const int wave = blk * 4 + wid;

    // Block-uniform panel + W2-fragment source.
    const __bf16 *psrc, *Wf;
    if (blk < 160) { psrc = vpi + (blk / 40) * (N_ * H1_);          Wf = W2fi; }
    else           { psrc = vpl + ((blk - 160) / 160) * (N_ * H1_); Wf = W2fl; }

    // 1) Panel -> LDS via async DMA, 16B/lane, straight copy (swizzle is
    //    pre-baked). Wave wid copies bytes [it*4096 + wid*1024, +1024).
    {
        const char* gp = (const char*)psrc;
        char* lp = (char*)panel;
#pragma unroll
        for (int it = 0; it < 10; ++it) {
            __builtin_amdgcn_global_load_lds(
                (const __attribute__((address_space(1))) void*)(gp + it * 4096 + t * 16),
                (__attribute__((address_space(3))) void*)(lp + it * 4096 + wid * 1024),
                16, 0, 0);
        }
    }

    // Wave-specific row params.
    const float* ubase;
    const float *b2, *w3;
    const float* b3p;
    long  obase;
    int   i;
    if (wave < B_ * N_) {                      // intra: W_t
        i = wave % N_;
        ubase = ui + wave * H1_;
        b2 = bi2; w3 = Wi3; b3p = bi3;
        obase = (long)wave * N_;
    } else {                                   // inter: A_lags_t
        const int w2i = wave - B_ * N_;
        i = w2i % N_;
        ubase = uq + w2i * H1_;
        b2 = bl2; w3 = Wl3; b3p = bl3;
        obase = (long)B_ * N_ * N_ + (long)w2i * N_;
    }
    const float b3f = b3p[0];

    // 2) W2 fragments: 16 coalesced 16B loads, register-resident.
    bf16x8 bfr[4][4];
#pragma unroll
    for (int kt = 0; kt < 4; ++kt)
#pragma unroll
        for (int ct = 0; ct < 4; ++ct)
            bfr[kt][ct] = *(const bf16x8*)(Wf + ((kt * 4 + ct) * 64 + lane) * 8);

    // u slices, split into even/odd k so they pair with dword-unpacked v.
    f32x4 ue[4], uo[4];
#pragma unroll
    for (int kt = 0; kt < 4; ++kt) {
        const f32x4 a0 = *(const f32x4*)(ubase + 32 * kt + 8 * q);
        const f32x4 a1 = *(const f32x4*)(ubase + 32 * kt + 8 * q + 4);
        ue[kt] = (f32x4){a0[0], a0[2], a1[0], a1[2]};
        uo[kt] = (f32x4){a0[1], a0[3], a1[1], a1[3]};
    }

    float b2c[4], w3c[4];
#pragma unroll
    for (int ct = 0; ct < 4; ++ct) {
        b2c[ct] = b2[16 * ct + c];
        w3c[ct] = w3[16 * ct + c];
    }

    __syncthreads();   // drains the global_load_lds DMA (vmcnt) + all waves

    // 3) Tile loop: LDS + registers only.
    for (int jt = 0; jt < 10; ++jt) {
        const __bf16* prow = panel + (16 * jt + c) * H1_;
        f32x4 acc[4];
#pragma unroll
        for (int ct = 0; ct < 4; ++ct)
            acc[ct] = (f32x4){b2c[ct], b2c[ct], b2c[ct], b2c[ct]};

#pragma unroll
        for (int kt = 0; kt < 4; ++kt) {
            const u32x4 vw = *(const u32x4*)(prow + (((4 * kt + q) ^ (c & 7)) << 3));
            // Unpack: dword d = [k=2d (lo16) | k=2d+1 (hi16)].
            f32x4 vlo, vhi;
#pragma unroll
            for (int d = 0; d < 4; ++d) {
                const unsigned lo = vw[d] << 16;
                const unsigned hi = vw[d] & 0xffff0000u;
                vlo[d] = __uint_as_float(lo);
                vhi[d] = __uint_as_float(hi);
            }
            f32x4 xe = ue[kt] + vlo;
            f32x4 xo = uo[kt] + vhi;
            xe = __builtin_elementwise_max(xe, (f32x4)0.f);
            xo = __builtin_elementwise_max(xo, (f32x4)0.f);
            union { bf16x8 v; unsigned d[4]; } a;
#pragma unroll
            for (int d = 0; d < 4; ++d)
                a.d[d] = pk_bf16(xe[d], xo[d]);
#pragma unroll
            for (int ct = 0; ct < 4; ++ct)
                acc[ct] = __builtin_amdgcn_mfma_f32_16x16x32_bf16(
                    a.v, bfr[kt][ct], acc[ct], 0, 0, 0);
        }

        // Epilogue: logit[r] = b3 + sum_col relu(H2pre) * w3 (b2 in acc).
        float logit[4];
#pragma unroll
        for (int r = 0; r < 4; ++r) {
            float p = 0.f;
#pragma unroll
            for (int ct = 0; ct < 4; ++ct)
                p += fmaxf(acc[ct][r], 0.f) * w3c[ct];
            p += __shfl_xor(p, 1);
            p += __shfl_xor(p, 2);
            p += __shfl_xor(p, 4);
            p += __shfl_xor(p, 8);
            logit[r] = p;
        }

        if (c < 4) {
            const int j = 16 * jt + 4 * q + c;
            const float lg = logit[c] + b3f;
            const float s = (j == i) ? 0.f : 1.f / (1.f + __expf(-lg));
            out[obase + j] = s;
        }
    }
}

// ---------------------------------------------------------------------------
extern "C" void kernel_launch(void* const* d_in, const int* in_sizes, int n_in,
                              void* d_out, int out_size, void* d_ws, size_t ws_size,
                              hipStream_t stream) {
    const float* ne  = (const float*)d_in[0];
    const float* zi  = (const float*)d_in[1];
    const float* ze  = (const float*)d_in[2];
    const float* lag = (const float*)d_in[3];
    const float* Wi1 = (const float*)d_in[4];
    const float* bi1 = (const float*)d_in[5];
    const float* Wi2 = (const float*)d_in[6];
    const float* bi2 = (const float*)d_in[7];
    const float* Wi3 = (const float*)d_in[8];
    const float* bi3 = (const float*)d_in[9];
    const float* Wl1 = (const float*)d_in[10];
    const float* bl1 = (const float*)d_in[11];
    const float* Wl2 = (const float*)d_in[12];
    const float* bl2 = (const float*)d_in[13];
    const float* Wl3 = (const float*)d_in[14];
    const float* bl3 = (const float*)d_in[15];

    float*  ws   = (float*)d_ws;
    float*  ui   = ws;                         // 640*128 fp32
    float*  uqw  = ws + 81920;                 // 2560*128 fp32
    __bf16* vpi  = (__bf16*)(ws + 409600);     // 640*128 bf16 (pre-swizzled)
    __bf16* vpl  = vpi + 81920;                // 640*128 bf16 (pre-swizzled)
    __bf16* W2fi = (__bf16*)(ws + 491520);     // 8192 bf16 (fragment order)
    __bf16* W2fl = W2fi + 8192;                // 8192 bf16

    stage_a<<<B_ * N_, 128, 0, stream>>>(ne, zi, ze, lag, Wi1, bi1, Wl1, bl1,
                                         Wi2, Wl2, ui, uqw, vpi, vpl, W2fi, W2fl);

    stage_b<<<(B_ * N_ + B_ * L_ * N_) / 4, 256, 0, stream>>>(
        ui, uqw, vpi, vpl, W2fi, W2fl,
        bi2, bi3, bl2, bl3, Wi3, Wl3,
        (float*)d_out);
}

// Round 9
// 113.075 us; speedup vs baseline: 1.3057x; 1.0193x over previous
//
#include <hip/hip_runtime.h>
#include <hip/hip_bf16.h>

// Problem constants
#define B_   4
#define N_   160
#define D_   64
#define ZI_  64
#define H1_  128
#define H2_  64
#define L_   4
#define LE_  8

typedef __bf16 bf16x8 __attribute__((ext_vector_type(8)));
typedef float  f32x4  __attribute__((ext_vector_type(4)));
typedef unsigned int u32x4 __attribute__((ext_vector_type(4)));

static __device__ __forceinline__ unsigned pk_bf16(float a, float b) {
    __hip_bfloat162 h = __float22bfloat162_rn(float2{a, b});
    union { __hip_bfloat162 h; unsigned u; } c;
    c.h = h;
    return c.u;
}

// ---------------------------------------------------------------------------
// Stage A: per-(b,i) precompute (scalar; ~3 µs).
//   ui[b,i,h]   = ne[b,i]@Wi1[:64] + z_intra[b]@Wi1[128:192] + bi1      (fp32)
//   uq[b,l,i,h] = ne[b,i]@Wl1[:64] + z_inter[b]@Wl1[128:192] + lag[l]@Wl1_l + bl1
//   vpi/vpl     = bf16 j-panels, stored PRE-SWIZZLED: logical element h of
//                 row bi lands at granule (h>>3)^(bi&7), elem h&7. Stage_b
//                 stages panels with a straight global_load_lds copy and
//                 reads with the same XOR formula (conflict-free, no ds_write).
// Blocks 0/1 also emit Wi2/Wl2 as bf16 MFMA-B-fragment-ordered arrays.
// ---------------------------------------------------------------------------
__global__ __launch_bounds__(128) void stage_a(
    const float* __restrict__ ne,
    const float* __restrict__ zi,
    const float* __restrict__ ze,
    const float* __restrict__ lag,
    const float* __restrict__ Wi1,
    const float* __restrict__ bi1,
    const float* __restrict__ Wl1,
    const float* __restrict__ bl1,
    const float* __restrict__ Wi2,
    const float* __restrict__ Wl2,
    float* __restrict__ ui, float* __restrict__ uq,
    __bf16* __restrict__ vpi, __bf16* __restrict__ vpl,
    __bf16* __restrict__ W2fi, __bf16* __restrict__ W2fl)
{
    const int bi = blockIdx.x;       // b*N + i
    const int b  = bi / N_;
    const int h  = threadIdx.x;      // 0..127

    const float* nerow = ne + bi * D_;

    float pi_ = 0.f, pj_ = 0.f, qi_ = 0.f, qj_ = 0.f;
#pragma unroll 16
    for (int d = 0; d < D_; ++d) {
        const float a = nerow[d];
        pi_ += a * Wi1[d * H1_ + h];
        pj_ += a * Wi1[(D_ + d) * H1_ + h];
        qi_ += a * Wl1[d * H1_ + h];
        qj_ += a * Wl1[(D_ + d) * H1_ + h];
    }
    float pz = 0.f, qz = 0.f;
#pragma unroll 16
    for (int z = 0; z < ZI_; ++z) {
        pz += zi[b * ZI_ + z] * Wi1[(2 * D_ + z) * H1_ + h];
        qz += ze[b * ZI_ + z] * Wl1[(2 * D_ + z) * H1_ + h];
    }

    ui[bi * H1_ + h] = pi_ + pz + bi1[h];

    // Pre-swizzled panel store (row&7 == bi&7 since N is a multiple of 8).
    const int hsw = (((h >> 3) ^ (bi & 7)) << 3) | (h & 7);
    vpi[bi * H1_ + hsw] = (__bf16)pj_;
    vpl[bi * H1_ + hsw] = (__bf16)qj_;

    const float qbase = qi_ + qz + bl1[h];
#pragma unroll
    for (int l = 0; l < L_; ++l) {
        float ql = 0.f;
#pragma unroll
        for (int e = 0; e < LE_; ++e)
            ql += lag[l * LE_ + e] * Wl1[(2 * D_ + ZI_ + e) * H1_ + h];
        uq[((b * L_ + l) * N_ + (bi % N_)) * H1_ + h] = qbase + ql;
    }

    // W2 -> bf16 fragment layout: chunk fc = (kt*4+ct)*64 + lane holds the 8
    // values lane needs for fragment (kt,ct).
    if (bi < 2) {
        const float* Wsrc = (bi == 0) ? Wi2 : Wl2;
        __bf16* Wdst = (bi == 0) ? W2fi : W2fl;
#pragma unroll
        for (int r = 0; r < 8; ++r) {
            const int fc = h + 128 * r;
            const int kt = fc >> 8, ct = (fc >> 6) & 3;
            const int q = (fc >> 4) & 3, c = fc & 15;
            bf16x8 t;
#pragma unroll
            for (int j = 0; j < 8; ++j)
                t[j] = (__bf16)Wsrc[(32 * kt + 8 * q + j) * H2_ + 16 * ct + c];
            *(bf16x8*)(Wdst + fc * 8) = t;
        }
    }
}

// ---------------------------------------------------------------------------
// Stage B (R9 = R8 + j-split x2): 1600 blocks x 256 thr. rowgrp = blk>>1
// (4 consecutive row-ids, same batch/branch); half = blk&1 -> j in
// [80*half, 80*half+80) = 5 tiles. Panel 80x128 bf16 (20 KB) staged via
// global_load_lds DMA (swizzle pre-baked by stage_a -> straight copy).
// Rationale: stage_b has been pinned at ~27us across scalar/packed builds,
// ds_write/DMA staging, 84..150 VGPRs -> ~80% all-wave stall. 3200 waves on
// an 8192-wave machine with 3 blocks/CU residency (800 blocks on 768 slots
// = 1.04 rounds + straggler tail) can't hide ds/shfl/LLC latency. Halve
// per-wave serial path, double block count; DMA keeps setup duplication to
// ~5 VMEM instrs (R6's register-staged split duplicated 20 VGPRs + ds_writes
// and regressed).
// MFMA 16x16x32 layouts (HW-verified):
//   A: lane holds A[m=lane&15][k=8*(lane>>4)+j]
//   B: lane holds B[k=8*(lane>>4)+j][n=lane&15]
//   C/D: lane holds D[row=4*(lane>>4)+reg][col=lane&15]
// ---------------------------------------------------------------------------
__global__ __launch_bounds__(256, 3) void stage_b(
    const float* __restrict__ ui, const float* __restrict__ uq,
    const __bf16* __restrict__ vpi, const __bf16* __restrict__ vpl,
    const __bf16* __restrict__ W2fi, const __bf16* __restrict__ W2fl,
    const float* __restrict__ bi2, const float* __restrict__ bi3,
    const float* __restrict__ bl2, const float* __restrict__ bl3,
    const float* __restrict__ Wi3, const float* __restrict__ Wl3,
    float* __restrict__ out)
{
    __shared__ __align__(16) __bf16 panel[80 * H1_];   // 20480 B, swizzled

    const int t    = threadIdx.x;
    const int wid  = t >> 6;
    const int lane = t & 63;
    const int q = lane >> 4;
    const int c = lane & 15;

    const int blk    = blockIdx.x;       // 0..1599
    const int rowgrp = blk >> 1;         // 0..799
    const int half   = blk & 1;          // j-half
    const int wave   = rowgrp * 4 + wid; // row id 0..3199

    // Block-uniform panel + W2-fragment source.
    const __bf16 *psrc, *Wf;
    if (rowgrp < 160) { psrc = vpi + (rowgrp / 40) * (N_ * H1_);          Wf = W2fi; }
    else              { psrc = vpl + ((rowgrp - 160) / 160) * (N_ * H1_); Wf = W2fl; }
    psrc += 80 * half * H1_;

    // 1) Panel -> LDS via async DMA, 16B/lane, straight copy (swizzle is
    //    pre-baked). Wave wid copies bytes [it*4096 + wid*1024, +1024).
    {
        const char* gp = (const char*)psrc;
        char* lp = (char*)panel;
#pragma unroll
        for (int it = 0; it < 5; ++it) {
            __builtin_amdgcn_global_load_lds(
                (const __attribute__((address_space(1))) void*)(gp + it * 4096 + t * 16),
                (__attribute__((address_space(3))) void*)(lp + it * 4096 + wid * 1024),
                16, 0, 0);
        }
    }

    // Wave-specific row params.
    const float* ubase;
    const float *b2, *w3;
    const float* b3p;
    long  obase;
    int   i;
    if (wave < B_ * N_) {                      // intra: W_t
        i = wave % N_;
        ubase = ui + wave * H1_;
        b2 = bi2; w3 = Wi3; b3p = bi3;
        obase = (long)wave * N_;
    } else {                                   // inter: A_lags_t
        const int w2i = wave - B_ * N_;
        i = w2i % N_;
        ubase = uq + w2i * H1_;
        b2 = bl2; w3 = Wl3; b3p = bl3;
        obase = (long)B_ * N_ * N_ + (long)w2i * N_;
    }
    const float b3f = b3p[0];

    // 2) W2 fragments: 16 coalesced 16B loads, register-resident.
    bf16x8 bfr[4][4];
#pragma unroll
    for (int kt = 0; kt < 4; ++kt)
#pragma unroll
        for (int ct = 0; ct < 4; ++ct)
            bfr[kt][ct] = *(const bf16x8*)(Wf + ((kt * 4 + ct) * 64 + lane) * 8);

    // u slices, split into even/odd k so they pair with dword-unpacked v.
    f32x4 ue[4], uo[4];
#pragma unroll
    for (int kt = 0; kt < 4; ++kt) {
        const f32x4 a0 = *(const f32x4*)(ubase + 32 * kt + 8 * q);
        const f32x4 a1 = *(const f32x4*)(ubase + 32 * kt + 8 * q + 4);
        ue[kt] = (f32x4){a0[0], a0[2], a1[0], a1[2]};
        uo[kt] = (f32x4){a0[1], a0[3], a1[1], a1[3]};
    }

    float b2c[4], w3c[4];
#pragma unroll
    for (int ct = 0; ct < 4; ++ct) {
        b2c[ct] = b2[16 * ct + c];
        w3c[ct] = w3[16 * ct + c];
    }

    __syncthreads();   // drains the global_load_lds DMA (vmcnt) + all waves

    // 3) Tile loop: LDS + registers only.
    for (int jt = 0; jt < 5; ++jt) {
        const __bf16* prow = panel + (16 * jt + c) * H1_;
        f32x4 acc[4];
#pragma unroll
        for (int ct = 0; ct < 4; ++ct)
            acc[ct] = (f32x4){b2c[ct], b2c[ct], b2c[ct], b2c[ct]};

#pragma unroll
        for (int kt = 0; kt < 4; ++kt) {
            const u32x4 vw = *(const u32x4*)(prow + (((4 * kt + q) ^ (c & 7)) << 3));
            // Unpack: dword d = [k=2d (lo16) | k=2d+1 (hi16)].
            f32x4 vlo, vhi;
#pragma unroll
            for (int d = 0; d < 4; ++d) {
                const unsigned lo = vw[d] << 16;
                const unsigned hi = vw[d] & 0xffff0000u;
                vlo[d] = __uint_as_float(lo);
                vhi[d] = __uint_as_float(hi);
            }
            f32x4 xe = ue[kt] + vlo;
            f32x4 xo = uo[kt] + vhi;
            xe = __builtin_elementwise_max(xe, (f32x4)0.f);
            xo = __builtin_elementwise_max(xo, (f32x4)0.f);
            union { bf16x8 v; unsigned d[4]; } a;
#pragma unroll
            for (int d = 0; d < 4; ++d)
                a.d[d] = pk_bf16(xe[d], xo[d]);
#pragma unroll
            for (int ct = 0; ct < 4; ++ct)
                acc[ct] = __builtin_amdgcn_mfma_f32_16x16x32_bf16(
                    a.v, bfr[kt][ct], acc[ct], 0, 0, 0);
        }

        // Epilogue: logit[r] = b3 + sum_col relu(H2pre) * w3 (b2 in acc).
        float logit[4];
#pragma unroll
        for (int r = 0; r < 4; ++r) {
            float p = 0.f;
#pragma unroll
            for (int ct = 0; ct < 4; ++ct)
                p += fmaxf(acc[ct][r], 0.f) * w3c[ct];
            p += __shfl_xor(p, 1);
            p += __shfl_xor(p, 2);
            p += __shfl_xor(p, 4);
            p += __shfl_xor(p, 8);
            logit[r] = p;
        }

        if (c < 4) {
            const int j = 80 * half + 16 * jt + 4 * q + c;
            const float lg = logit[c] + b3f;
            const float s = (j == i) ? 0.f : 1.f / (1.f + __expf(-lg));
            out[obase + j] = s;
        }
    }
}

// ---------------------------------------------------------------------------
extern "C" void kernel_launch(void* const* d_in, const int* in_sizes, int n_in,
                              void* d_out, int out_size, void* d_ws, size_t ws_size,
                              hipStream_t stream) {
    const float* ne  = (const float*)d_in[0];
    const float* zi  = (const float*)d_in[1];
    const float* ze  = (const float*)d_in[2];
    const float* lag = (const float*)d_in[3];
    const float* Wi1 = (const float*)d_in[4];
    const float* bi1 = (const float*)d_in[5];
    const float* Wi2 = (const float*)d_in[6];
    const float* bi2 = (const float*)d_in[7];
    const float* Wi3 = (const float*)d_in[8];
    const float* bi3 = (const float*)d_in[9];
    const float* Wl1 = (const float*)d_in[10];
    const float* bl1 = (const float*)d_in[11];
    const float* Wl2 = (const float*)d_in[12];
    const float* bl2 = (const float*)d_in[13];
    const float* Wl3 = (const float*)d_in[14];
    const float* bl3 = (const float*)d_in[15];

    float*  ws   = (float*)d_ws;
    float*  ui   = ws;                         // 640*128 fp32
    float*  uqw  = ws + 81920;                 // 2560*128 fp32
    __bf16* vpi  = (__bf16*)(ws + 409600);     // 640*128 bf16 (pre-swizzled)
    __bf16* vpl  = vpi + 81920;                // 640*128 bf16 (pre-swizzled)
    __bf16* W2fi = (__bf16*)(ws + 491520);     // 8192 bf16 (fragment order)
    __bf16* W2fl = W2fi + 8192;                // 8192 bf16

    stage_a<<<B_ * N_, 128, 0, stream>>>(ne, zi, ze, lag, Wi1, bi1, Wl1, bl1,
                                         Wi2, Wl2, ui, uqw, vpi, vpl, W2fi, W2fl);

    stage_b<<<2 * (B_ * N_ + B_ * L_ * N_) / 4, 256, 0, stream>>>(
        ui, uqw, vpi, vpl, W2fi, W2fl,
        bi2, bi3, bl2, bl3, Wi3, Wl3,
        (float*)d_out);
}

// Round 10
// 110.761 us; speedup vs baseline: 1.3329x; 1.0209x over previous
//
#include <hip/hip_runtime.h>
#include <hip/hip_bf16.h>

// Problem constants
#define B_   4
#define N_   160
#define D_   64
#define ZI_  64
#define H1_  128
#define H2_  64
#define L_   4
#define LE_  8

typedef __bf16 bf16x8 __attribute__((ext_vector_type(8)));
typedef float  f32x4  __attribute__((ext_vector_type(4)));
typedef unsigned int u32x4 __attribute__((ext_vector_type(4)));

static __device__ __forceinline__ unsigned pk_bf16(float a, float b) {
    __hip_bfloat162 h = __float22bfloat162_rn(float2{a, b});
    union { __hip_bfloat162 h; unsigned u; } c;
    c.h = h;
    return c.u;
}

// ---------------------------------------------------------------------------
// Stage A: per-(b,i) precompute (scalar; ~3 µs).
//   ui[b,i,h]   = ne[b,i]@Wi1[:64] + z_intra[b]@Wi1[128:192] + bi1      (fp32)
//   uq[b,l,i,h] = ne[b,i]@Wl1[:64] + z_inter[b]@Wl1[128:192] + lag[l]@Wl1_l + bl1
//   vpi/vpl     = bf16 j-panels, PRE-SWIZZLED (elem h -> granule (h>>3)^(bi&7))
//                 so stage_b DMA-copies them straight into LDS.
// Blocks 0/1 also pack the per-branch setup BLOB (contiguous, DMA-able):
//   [ W2 bf16 fragment-ordered 16384 B | b2 fp32 512 B | w3 fp32 512 B |
//     b3 fp32 4 B | pad -> 20480 B ]
// ---------------------------------------------------------------------------
__global__ __launch_bounds__(128) void stage_a(
    const float* __restrict__ ne,
    const float* __restrict__ zi,
    const float* __restrict__ ze,
    const float* __restrict__ lag,
    const float* __restrict__ Wi1,
    const float* __restrict__ bi1,
    const float* __restrict__ Wl1,
    const float* __restrict__ bl1,
    const float* __restrict__ Wi2,
    const float* __restrict__ bi2,
    const float* __restrict__ Wi3,
    const float* __restrict__ bi3,
    const float* __restrict__ Wl2,
    const float* __restrict__ bl2,
    const float* __restrict__ Wl3,
    const float* __restrict__ bl3,
    float* __restrict__ ui, float* __restrict__ uq,
    __bf16* __restrict__ vpi, __bf16* __restrict__ vpl,
    char* __restrict__ blob_i, char* __restrict__ blob_l)
{
    const int bi = blockIdx.x;       // b*N + i
    const int b  = bi / N_;
    const int h  = threadIdx.x;      // 0..127

    const float* nerow = ne + bi * D_;

    float pi_ = 0.f, pj_ = 0.f, qi_ = 0.f, qj_ = 0.f;
#pragma unroll 16
    for (int d = 0; d < D_; ++d) {
        const float a = nerow[d];
        pi_ += a * Wi1[d * H1_ + h];
        pj_ += a * Wi1[(D_ + d) * H1_ + h];
        qi_ += a * Wl1[d * H1_ + h];
        qj_ += a * Wl1[(D_ + d) * H1_ + h];
    }
    float pz = 0.f, qz = 0.f;
#pragma unroll 16
    for (int z = 0; z < ZI_; ++z) {
        pz += zi[b * ZI_ + z] * Wi1[(2 * D_ + z) * H1_ + h];
        qz += ze[b * ZI_ + z] * Wl1[(2 * D_ + z) * H1_ + h];
    }

    ui[bi * H1_ + h] = pi_ + pz + bi1[h];

    // Pre-swizzled panel store (row&7 == bi&7 since N is a multiple of 8).
    const int hsw = (((h >> 3) ^ (bi & 7)) << 3) | (h & 7);
    vpi[bi * H1_ + hsw] = (__bf16)pj_;
    vpl[bi * H1_ + hsw] = (__bf16)qj_;

    const float qbase = qi_ + qz + bl1[h];
#pragma unroll
    for (int l = 0; l < L_; ++l) {
        float ql = 0.f;
#pragma unroll
        for (int e = 0; e < LE_; ++e)
            ql += lag[l * LE_ + e] * Wl1[(2 * D_ + ZI_ + e) * H1_ + h];
        uq[((b * L_ + l) * N_ + (bi % N_)) * H1_ + h] = qbase + ql;
    }

    // Pack the setup blob for stage_b.
    if (bi < 2) {
        const float* Wsrc = (bi == 0) ? Wi2 : Wl2;
        char* blob = (bi == 0) ? blob_i : blob_l;
        __bf16* Wdst = (__bf16*)blob;
        // W2 -> bf16 fragment layout: chunk fc = (kt*4+ct)*64 + lane holds
        // the 8 values lane needs for fragment (kt,ct).
#pragma unroll
        for (int r = 0; r < 8; ++r) {
            const int fc = h + 128 * r;
            const int kt = fc >> 8, ct = (fc >> 6) & 3;
            const int q = (fc >> 4) & 3, c = fc & 15;
            bf16x8 t;
#pragma unroll
            for (int j = 0; j < 8; ++j)
                t[j] = (__bf16)Wsrc[(32 * kt + 8 * q + j) * H2_ + 16 * ct + c];
            *(bf16x8*)(Wdst + fc * 8) = t;
        }
        // Biases + w3 (fp32) appended.
        float* bdst = (float*)(blob + 16384);
        const float* b2s = (bi == 0) ? bi2 : bl2;
        const float* w3s = (bi == 0) ? Wi3 : Wl3;
        const float* b3s = (bi == 0) ? bi3 : bl3;
        if (h < H2_) bdst[h] = b2s[h];
        if (h < H2_) bdst[128 + h] = w3s[h];
        if (h == 0)  bdst[256] = b3s[0];
    }
}

// ---------------------------------------------------------------------------
// Stage B (R10): ALL hot data staged to LDS by one async DMA burst.
// 1600 blocks x 256 thr; rowgrp = blk>>1 (4 rows), half = blk&1 (5 j-tiles).
// LDS map: [panel 20480 B][blob 20480 B: W2frags+b2+w3+b3][u 2048 B] = 42 KB.
// Rationale: R2-R9 plateau (stage_b ~26-28us, ~10k cyc/wave vs ~1k issue
// work) is per-wave global setup latency: W2-frag/u/bias reads hit cross-XCD
// LLC (~600cyc) at ~2 resident waves/SIMD, and the allocator re-gathers W2
// per jt (VGPR=84 @R2). With everything in LDS, re-reads are ds_read (~12cyc)
// — allocator-proof — and setup latency is one DMA drain per block.
// MFMA 16x16x32 layouts (HW-verified):
//   A: lane holds A[m=lane&15][k=8*(lane>>4)+j]
//   B: lane holds B[k=8*(lane>>4)+j][n=lane&15]
//   C/D: lane holds D[row=4*(lane>>4)+reg][col=lane&15]
// ---------------------------------------------------------------------------
__global__ __launch_bounds__(256, 3) void stage_b(
    const float* __restrict__ ui, const float* __restrict__ uq,
    const __bf16* __restrict__ vpi, const __bf16* __restrict__ vpl,
    const char* __restrict__ blob_i, const char* __restrict__ blob_l,
    float* __restrict__ out)
{
    __shared__ __align__(16) char lds[43008];
    __bf16* panel = (__bf16*)lds;                 // 20480 B (80x128, swizzled)
    char*   blob  = lds + 20480;                  // 20480 B
    float*  ulds  = (float*)(lds + 40960);        // 2048 B (4 rows x 128 fp32)

    const int t    = threadIdx.x;
    const int wid  = t >> 6;
    const int lane = t & 63;
    const int q = lane >> 4;
    const int c = lane & 15;

    const int blk    = blockIdx.x;       // 0..1599
    const int rowgrp = blk >> 1;         // 0..799
    const int half   = blk & 1;          // j-half
    const int wave   = rowgrp * 4 + wid; // row id 0..3199
    const int wave0  = rowgrp * 4;       // block-uniform first row

    // Block-uniform sources.
    const __bf16* psrc;
    const char*   bsrc;
    const float*  usrc;
    if (rowgrp < 160) {                  // intra
        psrc = vpi + (rowgrp / 40) * (N_ * H1_);
        bsrc = blob_i;
        usrc = ui + wave0 * H1_;
    } else {                             // inter
        psrc = vpl + ((rowgrp - 160) / 160) * (N_ * H1_);
        bsrc = blob_l;
        usrc = uq + (wave0 - B_ * N_) * H1_;
    }
    psrc += 80 * half * H1_;

    // 1) One DMA burst: panel (5) + blob (5) + u (1, waves 0-1). 16B/lane.
    {
        const char* gp = (const char*)psrc;
#pragma unroll
        for (int it = 0; it < 5; ++it)
            __builtin_amdgcn_global_load_lds(
                (const __attribute__((address_space(1))) void*)(gp + it * 4096 + t * 16),
                (__attribute__((address_space(3))) void*)(lds + it * 4096 + wid * 1024),
                16, 0, 0);
#pragma unroll
        for (int it = 0; it < 5; ++it)
            __builtin_amdgcn_global_load_lds(
                (const __attribute__((address_space(1))) void*)(bsrc + it * 4096 + t * 16),
                (__attribute__((address_space(3))) void*)(blob + it * 4096 + wid * 1024),
                16, 0, 0);
        if (wid < 2)
            __builtin_amdgcn_global_load_lds(
                (const __attribute__((address_space(1))) void*)((const char*)usrc + t * 16),
                (__attribute__((address_space(3))) void*)((char*)ulds + wid * 1024),
                16, 0, 0);
    }

    // Wave-specific output params (pure ALU, overlaps DMA).
    long obase;
    int  i;
    if (wave < B_ * N_) {
        i = wave % N_;
        obase = (long)wave * N_;
    } else {
        const int w2i = wave - B_ * N_;
        i = w2i % N_;
        obase = (long)B_ * N_ * N_ + (long)w2i * N_;
    }

    __syncthreads();   // drains DMA (vmcnt) for all waves

    // 2) Setup from LDS.
    bf16x8 bfr[4][4];
#pragma unroll
    for (int kt = 0; kt < 4; ++kt)
#pragma unroll
        for (int ct = 0; ct < 4; ++ct)
            bfr[kt][ct] = *(const bf16x8*)(blob + ((kt * 4 + ct) * 64 + lane) * 16);

    const float* bf32 = (const float*)(blob + 16384);
    float b2c[4], w3c[4];
#pragma unroll
    for (int ct = 0; ct < 4; ++ct) {
        b2c[ct] = bf32[16 * ct + c];
        w3c[ct] = bf32[128 + 16 * ct + c];
    }
    const float b3f = bf32[256];

    const float* ubase = ulds + wid * H1_;
    f32x4 ue[4], uo[4];
#pragma unroll
    for (int kt = 0; kt < 4; ++kt) {
        const f32x4 a0 = *(const f32x4*)(ubase + 32 * kt + 8 * q);
        const f32x4 a1 = *(const f32x4*)(ubase + 32 * kt + 8 * q + 4);
        ue[kt] = (f32x4){a0[0], a0[2], a1[0], a1[2]};
        uo[kt] = (f32x4){a0[1], a0[3], a1[1], a1[3]};
    }

    // 3) Tile loop: LDS + registers only.
    for (int jt = 0; jt < 5; ++jt) {
        const __bf16* prow = panel + (16 * jt + c) * H1_;
        f32x4 acc[4];
#pragma unroll
        for (int ct = 0; ct < 4; ++ct)
            acc[ct] = (f32x4){b2c[ct], b2c[ct], b2c[ct], b2c[ct]};

#pragma unroll
        for (int kt = 0; kt < 4; ++kt) {
            const u32x4 vw = *(const u32x4*)(prow + (((4 * kt + q) ^ (c & 7)) << 3));
            f32x4 vlo, vhi;
#pragma unroll
            for (int d = 0; d < 4; ++d) {
                vlo[d] = __uint_as_float(vw[d] << 16);
                vhi[d] = __uint_as_float(vw[d] & 0xffff0000u);
            }
            f32x4 xe = ue[kt] + vlo;
            f32x4 xo = uo[kt] + vhi;
            xe = __builtin_elementwise_max(xe, (f32x4)0.f);
            xo = __builtin_elementwise_max(xo, (f32x4)0.f);
            union { bf16x8 v; unsigned d[4]; } a;
#pragma unroll
            for (int d = 0; d < 4; ++d)
                a.d[d] = pk_bf16(xe[d], xo[d]);
#pragma unroll
            for (int ct = 0; ct < 4; ++ct)
                acc[ct] = __builtin_amdgcn_mfma_f32_16x16x32_bf16(
                    a.v, bfr[kt][ct], acc[ct], 0, 0, 0);
        }

        // Epilogue: logit[r] = b3 + sum_col relu(H2pre) * w3 (b2 in acc).
        float logit[4];
#pragma unroll
        for (int r = 0; r < 4; ++r) {
            float p = 0.f;
#pragma unroll
            for (int ct = 0; ct < 4; ++ct)
                p += fmaxf(acc[ct][r], 0.f) * w3c[ct];
            p += __shfl_xor(p, 1);
            p += __shfl_xor(p, 2);
            p += __shfl_xor(p, 4);
            p += __shfl_xor(p, 8);
            logit[r] = p;
        }

        if (c < 4) {
            const int j = 80 * half + 16 * jt + 4 * q + c;
            const float lg = logit[c] + b3f;
            const float s = (j == i) ? 0.f : 1.f / (1.f + __expf(-lg));
            out[obase + j] = s;
        }
    }
}

// ---------------------------------------------------------------------------
extern "C" void kernel_launch(void* const* d_in, const int* in_sizes, int n_in,
                              void* d_out, int out_size, void* d_ws, size_t ws_size,
                              hipStream_t stream) {
    const float* ne  = (const float*)d_in[0];
    const float* zi  = (const float*)d_in[1];
    const float* ze  = (const float*)d_in[2];
    const float* lag = (const float*)d_in[3];
    const float* Wi1 = (const float*)d_in[4];
    const float* bi1 = (const float*)d_in[5];
    const float* Wi2 = (const float*)d_in[6];
    const float* bi2 = (const float*)d_in[7];
    const float* Wi3 = (const float*)d_in[8];
    const float* bi3 = (const float*)d_in[9];
    const float* Wl1 = (const float*)d_in[10];
    const float* bl1 = (const float*)d_in[11];
    const float* Wl2 = (const float*)d_in[12];
    const float* bl2 = (const float*)d_in[13];
    const float* Wl3 = (const float*)d_in[14];
    const float* bl3 = (const float*)d_in[15];

    float*  ws     = (float*)d_ws;
    float*  ui     = ws;                        // 640*128 fp32
    float*  uqw    = ws + 81920;                // 2560*128 fp32
    __bf16* vpi    = (__bf16*)(ws + 409600);    // 640*128 bf16 (pre-swizzled)
    __bf16* vpl    = vpi + 81920;               // 640*128 bf16 (pre-swizzled)
    char*   blob_i = (char*)d_ws + 1966080;     // 20480 B setup blob (intra)
    char*   blob_l = blob_i + 20480;            // 20480 B setup blob (inter)

    stage_a<<<B_ * N_, 128, 0, stream>>>(ne, zi, ze, lag, Wi1, bi1, Wl1, bl1,
                                         Wi2, bi2, Wi3, bi3, Wl2, bl2, Wl3, bl3,
                                         ui, uqw, vpi, vpl, blob_i, blob_l);

    stage_b<<<2 * (B_ * N_ + B_ * L_ * N_) / 4, 256, 0, stream>>>(
        ui, uqw, vpi, vpl, blob_i, blob_l,
        (float*)d_out);
}